// Round 1
// baseline (237.137 us; speedup 1.0000x reference)
//
#include <hip/hip_runtime.h>

#define HW 4096  // 64*64 spatial

// Static device scratch (24 MiB): qkv[m][b][o][h][w] fp32, m in {0:q,1:k,2:v}.
// Fully rewritten by qkv_proj before attn reads it on every launch -> graph-safe.
__device__ float g_qkv[3 * 8 * 64 * HW];

#if __has_builtin(__builtin_amdgcn_exp2f)
#define QSCALE 1.4426950408889634f            // prescale q by log2(e); exp2 is native v_exp_f32
__device__ __forceinline__ float fexp(float l) { return __builtin_amdgcn_exp2f(l); }
#else
#define QSCALE 1.0f
__device__ __forceinline__ float fexp(float l) { return __expf(l); }
#endif

// R8 qkv: W reads moved OFF the LDS unit onto the scalar pipe.
// R4-R7 (~45us) were LDS-issue-bound: per c-chunk per wave, 4 b128 + 48
// broadcast-b32 W reads ~ 150-330 LDS-unit cyc vs 384 VALU cyc, with 8 waves
// feeding ONE LDS unit but only 2 waves per SIMD -> unit oversubscribed ~2x.
// Now: grid 2048 = (os,b,h); wave owns o = os*16+wave*4 .. +3 (wave-uniform),
// thread owns one w column. W loads have uniform addresses -> s_load_dwordx4
// into SGPRs, FMA = v_fmac_f32 v,s,v. LDS per chunk per wave: 4 b32 (xa only).
// LDS total 17.4 KB -> 8 blocks/CU = 8 waves/SIMD (was 2) hides the per-chunk
// lgkmcnt(0) s_load drain. Sibling os-blocks of one (b,h) sit 512 apart
// (512%8==0 -> same XCD slot) so the 4x re-staged x row stays L2-resident.
__global__ __launch_bounds__(256, 8) void qkv_proj(
    const float* __restrict__ x,
    const float* __restrict__ wq,
    const float* __restrict__ wk,
    const float* __restrict__ wv)
{
    __shared__ float xs[64][68];      // [c][w], stride 68: f4 rows 16B-aligned,
                                      // staging writes conflict-free (4c+w banks)
    const int t  = threadIdx.x;
    const int os = blockIdx.x >> 9;          // o-slice 0..3
    const int b  = (blockIdx.x >> 6) & 7;
    const int h  = blockIdx.x & 63;

    const float* __restrict__ xrow = x + (size_t)b * 64 * HW + (size_t)h * 64;
    #pragma unroll
    for (int i = t; i < 1024; i += 256) {    // 4 iters, float4 coalesced
        int c = i >> 4, w4 = (i & 15) << 2;
        *(float4*)&xs[c][w4] = *(const float4*)&xrow[(size_t)c * HW + w4];
    }
    __syncthreads();

    const int lane  = t & 63;                              // w column
    const int wave  = __builtin_amdgcn_readfirstlane(t >> 6);
    const int obase = os * 16 + wave * 4;                  // wave-uniform!

    const float* __restrict__ wmat[3] = { wq, wk, wv };
    float acc[3][4];
    #pragma unroll
    for (int m = 0; m < 3; ++m)
        #pragma unroll
        for (int oi = 0; oi < 4; ++oi) acc[m][oi] = 0.f;

    #pragma unroll 2
    for (int cq = 0; cq < 16; ++cq) {
        const int c0 = cq * 4;
        float xa[4];
        #pragma unroll
        for (int ci = 0; ci < 4; ++ci)
            xa[ci] = xs[c0 + ci][lane];      // b32, consecutive lanes: 2-way=free
        #pragma unroll
        for (int m = 0; m < 3; ++m) {
            #pragma unroll
            for (int oi = 0; oi < 4; ++oi) {
                // uniform address -> s_load_dwordx4, lives in SGPRs
                const float4 wf = *(const float4*)&wmat[m][(obase + oi) * 64 + c0];
                acc[m][oi] = fmaf(wf.x, xa[0], acc[m][oi]);
                acc[m][oi] = fmaf(wf.y, xa[1], acc[m][oi]);
                acc[m][oi] = fmaf(wf.z, xa[2], acc[m][oi]);
                acc[m][oi] = fmaf(wf.w, xa[3], acc[m][oi]);
            }
        }
    }

    #pragma unroll
    for (int m = 0; m < 3; ++m)
        #pragma unroll
        for (int oi = 0; oi < 4; ++oi)
            g_qkv[((size_t)(m * 8 + b) * 64 + obase + oi) * HW + (size_t)h * 64 + lane]
                = acc[m][oi];                // b32 stores, lanes consecutive
}

// R8 attn: 2-way row split for occupancy. One block per (b,o,half): rows
// R0..R0+31 with 38x70 k/v halo in LDS (20.8 KB -> 4 blocks/CU = 4 waves/SIMD,
// was 2). Thread owns a 2x4 pixel tile: halo union 8x10 taps, 392 exp/thread
// (total exp work unchanged -- this only buys latency hiding for staging loads,
// trans-pipe exp, and syncthreads). Halves of one (b,o) sit 512 apart -> same
// XCD slot, shared halo rows L2-hit.
// rel_w/rel_h dead (constant along 49-entry softmax axis -> shift-invariance).
// Zero padding + 1x1 conv => k=v=0 outside; logit q*0=0 still participates.
// k at kv[r][0..69], v at kv[r][70..139]: pair -> ds_read2_b32 offsets 0/70.
__global__ __launch_bounds__(256, 4) void attn(float* __restrict__ out)
{
    __shared__ float kv[38][140];     // 20.8 KB
    const int t  = threadIdx.x;
    const int hb = blockIdx.x >> 9;          // row half 0..1
    const int b  = (blockIdx.x >> 6) & 7;
    const int o  = blockIdx.x & 63;
    const int R0 = hb * 32;

    const float* qb = g_qkv + ((size_t)(0 * 8 + b) * 64 + o) * HW;
    const float* kb = g_qkv + ((size_t)(1 * 8 + b) * 64 + o) * HW;
    const float* vb = g_qkv + ((size_t)(2 * 8 + b) * 64 + o) * HW;

    for (int i = t; i < 38 * 70; i += 256) {
        int r = i / 70, c = i - r * 70;
        int gh = R0 + r - 3, gw = c - 3;
        float kk = 0.f, vv = 0.f;
        if ((unsigned)gh < 64u && (unsigned)gw < 64u) {
            kk = kb[gh * 64 + gw];
            vv = vb[gh * 64 + gw];
        }
        kv[r][c] = kk;
        kv[r][70 + c] = vv;
    }
    __syncthreads();

    const int r0 = (t >> 4) * 2;      // pixel-tile row base within half (0..30)
    const int c0 = (t & 15) * 4;      // pixel-tile col base (0..60)

    float qv[8], den[8], num[8];
    #pragma unroll
    for (int i = 0; i < 2; ++i) {
        float4 q4 = *(const float4*)&qb[(size_t)(R0 + r0 + i) * 64 + c0];
        qv[i * 4 + 0] = q4.x * QSCALE; qv[i * 4 + 1] = q4.y * QSCALE;
        qv[i * 4 + 2] = q4.z * QSCALE; qv[i * 4 + 3] = q4.w * QSCALE;
    }
    #pragma unroll
    for (int i = 0; i < 8; ++i) { den[i] = 0.f; num[i] = 0.f; }

    // halo rows r0..r0+7, cols c0..c0+9; pixel (i,j) active iff rr-i,cc-j in [0,7)
    #pragma unroll
    for (int rr = 0; rr < 8; ++rr) {
        #pragma unroll
        for (int cc = 0; cc < 10; ++cc) {
            const float kk = kv[r0 + rr][c0 + cc];        // pair -> ds_read2_b32
            const float vv = kv[r0 + rr][70 + c0 + cc];
            #pragma unroll
            for (int i = 0; i < 2; ++i) {
                if (rr - i >= 0 && rr - i < 7) {          // compile-time predicates
                    #pragma unroll
                    for (int j = 0; j < 4; ++j) {
                        if (cc - j >= 0 && cc - j < 7) {
                            float e = fexp(qv[i * 4 + j] * kk);
                            den[i * 4 + j] += e;
                            num[i * 4 + j] = fmaf(e, vv, num[i * 4 + j]);
                        }
                    }
                }
            }
        }
    }

    float* ob = out + ((size_t)(b * 64 + o)) * HW;
    #pragma unroll
    for (int i = 0; i < 2; ++i) {
        float4 v = { num[i * 4 + 0] / den[i * 4 + 0], num[i * 4 + 1] / den[i * 4 + 1],
                     num[i * 4 + 2] / den[i * 4 + 2], num[i * 4 + 3] / den[i * 4 + 3] };
        *(float4*)&ob[(size_t)(R0 + r0 + i) * 64 + c0] = v;
    }
}

extern "C" void kernel_launch(void* const* d_in, const int* in_sizes, int n_in,
                              void* d_out, int out_size, void* d_ws, size_t ws_size,
                              hipStream_t stream)
{
    // d_in: 0=x, 1=wq, 2=wk, 3=wv (fp32), 4=rel_w, 5=rel_h (dead: softmax
    // shift-invariance), 6=kernel_size(7), 7=padding(3) hardcoded.
    qkv_proj<<<dim3(2048), dim3(256), 0, stream>>>(
        (const float*)d_in[0], (const float*)d_in[1],
        (const float*)d_in[2], (const float*)d_in[3]);
    attn<<<dim3(1024), dim3(256), 0, stream>>>((float*)d_out);
}